// Round 17
// baseline (1036.563 us; speedup 1.0000x reference)
//
#include <hip/hip_runtime.h>

#define HN 192
#define TT 2048
#define NCLS 12
#define ROWB 768
// LDS layout (bytes)
#define L0_PAD    147456           // 2048B zero region (pad reads land here)
#define LDS_LIST0 149504           // 1024B data slots + 256B junk
#define LDS_LIST1 150784           // same for layer 1
#define LDS_S0    152064           // 2 x 1024B s0 double buffer (parity)
#define LDS_FEAT  154112           // 768B
#define LDS_TOTAL 154880

// ws layout (floats): [w0 rows 0..191][zero row][w1 rows 0..191][1024B pad]
__global__ void snn_pack_k(const float* __restrict__ Wc, float* __restrict__ ws) {
  int idx = blockIdx.x * 256 + threadIdx.x;
  if (idx < HN * HN) {                       // layer 0: Wc[0][i][j] -> ws[j*192+i]
    int i = idx / HN, j = idx % HN;
    ws[j * HN + i] = Wc[idx];
  } else if (idx < 2 * HN * HN) {            // layer 1 -> rows 193..384
    int r = idx - HN * HN;
    int i = r / HN, j = r % HN;
    ws[(193 + j) * HN + i] = Wc[idx];
  } else {
    int r = idx - 2 * HN * HN;
    if (r < HN) ws[192 * HN + r] = 0.0f;     // zero row
    if (r < 256) ws[385 * HN + r] = 0.0f;    // tail pad
  }
}

__device__ __forceinline__ float4 add4(float4 a, float4 b) {
  return make_float4(a.x + b.x, a.y + b.y, a.z + b.z, a.w + b.w);
}
__device__ __forceinline__ int lanecnt_lt(unsigned long long m) {
  return __builtin_amdgcn_mbcnt_hi((unsigned)(m >> 32),
           __builtin_amdgcn_mbcnt_lo((unsigned)m, 0u));
}

#define READC(da, db, base, c) do { \
  da = *(const int4*)((base) + (c) * 32); \
  db = *(const int4*)((base) + (c) * 32 + 16); } while (0)

#define ISS8Q(p, ca, cb, basep) do { \
  p##0 = *(const float4*)((basep) + (unsigned)(ca).x + ln16); \
  p##1 = *(const float4*)((basep) + (unsigned)(ca).y + ln16); \
  p##2 = *(const float4*)((basep) + (unsigned)(ca).z + ln16); \
  p##3 = *(const float4*)((basep) + (unsigned)(ca).w + ln16); \
  p##4 = *(const float4*)((basep) + (unsigned)(cb).x + ln16); \
  p##5 = *(const float4*)((basep) + (unsigned)(cb).y + ln16); \
  p##6 = *(const float4*)((basep) + (unsigned)(cb).z + ln16); \
  p##7 = *(const float4*)((basep) + (unsigned)(cb).w + ln16); } while (0)

#define CONS8Q(acc, p) acc = add4(acc, \
  add4(add4(add4(p##0, p##1), add4(p##2, p##3)), \
       add4(add4(p##4, p##5), add4(p##6, p##7))))

// 2 waves per batch, one-step-lagged pipeline (r16 structure) with the
// post-gather LIF chain shortened: zh = (z-part)*0.5 + v*0.5 precomputed
// during the gather wait, so the post-gather path is one fma + cmp per word
// (r9's association, measured absmax 0.0 on this data).
__global__ __launch_bounds__(128, 1) void snn_main_k(
    const float* __restrict__ x, const float* __restrict__ W_in,
    const float* __restrict__ b_in, const float* __restrict__ b_cells,
    const float* __restrict__ W_head, const float* __restrict__ b_head,
    const float* __restrict__ ws, float* __restrict__ out)
{
  extern __shared__ char lds[];
  const int tid = threadIdx.x;
  const int ln  = tid & 63;
  const bool isW0 = (tid < 64);
  const int b   = blockIdx.x;
  const unsigned ln16 = (unsigned)ln << 4;
  const char* ldsb = lds;
  char* list0b = lds + LDS_LIST0;
  char* list1b = lds + LDS_LIST1;
  float* feat  = (float*)(lds + LDS_FEAT);
  const char* w1zb = (const char*)ws + 192 * ROWB;   // zero row = L1 offset base

  // stage W0 (9216 float4) + 2048B zero guard (both waves)
  {
    const float4* src = (const float4*)ws;
    float4* dst = (float4*)lds;
    for (int i = tid; i < (192 * ROWB) / 16; i += 128) dst[i] = src[i];
    ((float4*)(lds + L0_PAD))[tid] = make_float4(0.f, 0.f, 0.f, 0.f);
  }
  __syncthreads();

  // opaque zero: forces x loads to VMEM so lgkm counter stays purely DS
  int vz;
  asm volatile("v_mov_b32 %0, 0" : "=v"(vz));

  // per-lane constants (4 neurons/lane in both layers; lanes 48-63 parked)
  float wi0[4], wi1[4], wi2[4], zb[4], b1z[4];
  #pragma unroll
  for (int k = 0; k < 4; ++k) {
    int i = 4 * ln + k;
    bool a = (i < HN);
    int ii = a ? i : 0;
    wi0[k] = a ? W_in[ii * 3 + 0] : 0.f;
    wi1[k] = a ? W_in[ii * 3 + 1] : 0.f;
    wi2[k] = a ? W_in[ii * 3 + 2] : 0.f;
    zb[k]  = a ? (b_in[ii] + b_cells[ii]) : -1e30f;
    b1z[k] = a ? b_cells[HN + ii] : -1e30f;
  }
  const float* __restrict__ xb = x + (size_t)b * TT * 3;
  const int vo = ln * 3072;

  // wave0 state: chunks preset to pad offsets (iter0 gathers zeros)
  float v0k[4] = {0, 0, 0, 0};
  int n0 = 0;
  int4 c0a = {L0_PAD,L0_PAD,L0_PAD,L0_PAD}, c0b = c0a, c1a = c0a, c1b = c0a;
  float x0 = xb[vz + 0], x1 = xb[vz + 1], x2 = xb[vz + 2];
  // wave1 state
  float v1k[4] = {0, 0, 0, 0}, cntk[4] = {0, 0, 0, 0};
  int n1 = 0;
  float4 gA0, gA1, gA2, gA3, gA4, gA5, gA6, gA7;
  float4 gB0, gB1, gB2, gB3, gB4, gB5, gB6, gB7;
  if (!isW0) {
    // pre-loop: issue an initial pad gather (zero row) so iter1's consume is safe
    int4 dz = {0, 0, 0, 0};
    ISS8Q(gA, dz, dz, w1zb);
    gB0=gB1=gB2=gB3=gB4=gB5=gB6=gB7=make_float4(0.f,0.f,0.f,0.f);
  }

  #pragma unroll 1
  for (int i = 0; i <= TT; ++i) {
    if (isW0) {
      if (i < TT) {
        // ======== wave 0: layer-0 step i ========
        const int wp = i & 1;
        float4 a0v = make_float4(0.f, 0.f, 0.f, 0.f);
        float4 hA0, hA1, hA2, hA3, hA4, hA5, hA6, hA7;
        float4 hB0, hB1, hB2, hB3, hB4, hB5, hB6, hB7;
        ISS8Q(hA, c0a, c0b, ldsb);             // unconditional group 0
        if (n0 > 8) ISS8Q(hB, c1a, c1b, ldsb);
        // zh precompute DURING the gather wait: v_new = zh + a0*0.5
        float zh[4];
        #pragma unroll
        for (int k = 0; k < 4; ++k)
          zh[k] = (x0 * wi0[k] + x1 * wi1[k] + x2 * wi2[k] + zb[k]) * 0.5f
                + v0k[k] * 0.5f;
        const int tn = (i + 1 < TT) ? i + 1 : 0;
        const float nx0 = xb[tn * 3 + vz + 0];
        const float nx1 = xb[tn * 3 + vz + 1];
        const float nx2 = xb[tn * 3 + vz + 2];
        CONS8Q(a0v, hA);
        if (n0 > 8) CONS8Q(a0v, hB);
        if (n0 > 16) {                          // rare overflow: chunks 2..3 + loop
          int4 e2a, e2b;
          float4 r0, r1, r2, r3, r4, r5, r6, r7;
          READC(e2a, e2b, list0b, 2);
          ISS8Q(r, e2a, e2b, ldsb);
          CONS8Q(a0v, r);
          if (n0 > 24) {
            READC(e2a, e2b, list0b, 3);
            ISS8Q(r, e2a, e2b, ldsb);
            CONS8Q(a0v, r);
          }
          if (n0 > 32) {
            #pragma unroll 1
            for (int g = 4; g * 8 < n0; ++g) {
              READC(e2a, e2b, list0b, g);
              ISS8Q(r, e2a, e2b, ldsb);
              CONS8Q(a0v, r);
            }
          }
        }
        // LIF layer 0: single fma + cmp per word on the post-gather path
        const float a0arr[4] = {a0v.x, a0v.y, a0v.z, a0v.w};
        float s0f[4];
        bool sp[4];
        unsigned long long mm0, mm1, mm2, mm3;
        {
          float v;
          v = zh[0] + a0arr[0] * 0.5f;
          sp[0] = (v >= 1.0f); mm0 = __ballot(sp[0] ? 1 : 0);
          s0f[0] = sp[0] ? 1.0f : 0.0f; v0k[0] = sp[0] ? 0.0f : v;
          v = zh[1] + a0arr[1] * 0.5f;
          sp[1] = (v >= 1.0f); mm1 = __ballot(sp[1] ? 1 : 0);
          s0f[1] = sp[1] ? 1.0f : 0.0f; v0k[1] = sp[1] ? 0.0f : v;
          v = zh[2] + a0arr[2] * 0.5f;
          sp[2] = (v >= 1.0f); mm2 = __ballot(sp[2] ? 1 : 0);
          s0f[2] = sp[2] ? 1.0f : 0.0f; v0k[2] = sp[2] ? 0.0f : v;
          v = zh[3] + a0arr[3] * 0.5f;
          sp[3] = (v >= 1.0f); mm3 = __ballot(sp[3] ? 1 : 0);
          s0f[3] = sp[3] ? 1.0f : 0.0f; v0k[3] = sp[3] ? 0.0f : v;
        }
        // publish s0(i) — unconditional (1024B slot; parked lanes write 0)
        *(float4*)(lds + LDS_S0 + (wp << 10) + ln16) =
            make_float4(s0f[0], s0f[1], s0f[2], s0f[3]);
        // branchless compaction: cndmask'd slot (junk slots at 256+ln)
        const int q0   = (int)__popcll(mm0);
        const int q01  = q0  + (int)__popcll(mm1);
        const int q012 = q01 + (int)__popcll(mm2);
        const int p0n  = q012 + (int)__popcll(mm3);
        const int jk = 256 + ln;
        {
          int s;
          s = sp[0] ? lanecnt_lt(mm0)          : jk; *(int*)(list0b + 4 * s) = vo;
          s = sp[1] ? (q0   + lanecnt_lt(mm1)) : jk; *(int*)(list0b + 4 * s) = vo + ROWB;
          s = sp[2] ? (q01  + lanecnt_lt(mm2)) : jk; *(int*)(list0b + 4 * s) = vo + 2 * ROWB;
          s = sp[3] ? (q012 + lanecnt_lt(mm3)) : jk; *(int*)(list0b + 4 * s) = vo + 3 * ROWB;
        }
        *(int*)(list0b + 4 * (p0n + ln)) = L0_PAD;   // unconditional pads
        n0 = p0n;
        asm volatile("" ::: "memory");
        READC(c0a, c0b, list0b, 0);
        READC(c1a, c1b, list0b, 1);
        // oldest DS ops (s0 publish, compaction) retired; chunk reads stay out
        asm volatile("s_waitcnt lgkmcnt(8)" ::: "memory");
        x0 = nx0; x1 = nx1; x2 = nx2;
      }
    } else {
      if (i > 0) {
        // ======== wave 1: layer-1 step i-1 ========
        const int rp = (i - 1) & 1;
        const float4 s0v = *(const float4*)(lds + LDS_S0 + (rp << 10) + ln16);
        // vh precompute during the consume (independent of gather data)
        float vh[4];
        #pragma unroll
        for (int k = 0; k < 4; ++k) vh[k] = v1k[k] * 0.5f + b1z[k] * 0.5f;
        // consume W1 gather (issued at end of previous block -> real flight)
        float4 a1v = make_float4(0.f, 0.f, 0.f, 0.f);
        CONS8Q(a1v, gA);                        // unconditional group 0
        if (n1 > 8) CONS8Q(a1v, gB);
        if (n1 > 16) {                          // rare overflow
          int4 e2a, e2b;
          float4 r0, r1, r2, r3, r4, r5, r6, r7;
          READC(e2a, e2b, list1b, 2);
          ISS8Q(r, e2a, e2b, w1zb);
          CONS8Q(a1v, r);
          if (n1 > 24) {
            READC(e2a, e2b, list1b, 3);
            ISS8Q(r, e2a, e2b, w1zb);
            CONS8Q(a1v, r);
          }
          if (n1 > 32) {
            #pragma unroll 1
            for (int g = 4; g * 8 < n1; ++g) {
              READC(e2a, e2b, list1b, g);
              ISS8Q(r, e2a, e2b, w1zb);
              CONS8Q(a1v, r);
            }
          }
        }
        // LIF layer 1: v = vh + (a1+s0)*0.5 (2 serial ops post-consume)
        const float a1arr[4] = {a1v.x + s0v.x, a1v.y + s0v.y,
                                a1v.z + s0v.z, a1v.w + s0v.w};
        float s1w[4];
        bool sq[4];
        unsigned long long nn0, nn1, nn2, nn3;
        {
          float v;
          v = vh[0] + a1arr[0] * 0.5f;
          sq[0] = (v >= 1.0f); nn0 = __ballot(sq[0] ? 1 : 0);
          s1w[0] = sq[0] ? 1.0f : 0.0f; v1k[0] = sq[0] ? 0.0f : v;
          v = vh[1] + a1arr[1] * 0.5f;
          sq[1] = (v >= 1.0f); nn1 = __ballot(sq[1] ? 1 : 0);
          s1w[1] = sq[1] ? 1.0f : 0.0f; v1k[1] = sq[1] ? 0.0f : v;
          v = vh[2] + a1arr[2] * 0.5f;
          sq[2] = (v >= 1.0f); nn2 = __ballot(sq[2] ? 1 : 0);
          s1w[2] = sq[2] ? 1.0f : 0.0f; v1k[2] = sq[2] ? 0.0f : v;
          v = vh[3] + a1arr[3] * 0.5f;
          sq[3] = (v >= 1.0f); nn3 = __ballot(sq[3] ? 1 : 0);
          s1w[3] = sq[3] ? 1.0f : 0.0f; v1k[3] = sq[3] ? 0.0f : v;
        }
        cntk[0] += s1w[0]; cntk[1] += s1w[1]; cntk[2] += s1w[2]; cntk[3] += s1w[3];
        // branchless compaction (junk slots at 256+ln; pad value 0 -> zero row)
        const int r0c  = (int)__popcll(nn0);
        const int r01  = r0c + (int)__popcll(nn1);
        const int r012 = r01 + (int)__popcll(nn2);
        const int p1n  = r012 + (int)__popcll(nn3);
        const int jk = 256 + ln;
        {
          int s;
          s = sq[0] ? lanecnt_lt(nn0)          : jk; *(int*)(list1b + 4 * s) = vo + ROWB;
          s = sq[1] ? (r0c  + lanecnt_lt(nn1)) : jk; *(int*)(list1b + 4 * s) = vo + 2 * ROWB;
          s = sq[2] ? (r01  + lanecnt_lt(nn2)) : jk; *(int*)(list1b + 4 * s) = vo + 3 * ROWB;
          s = sq[3] ? (r012 + lanecnt_lt(nn3)) : jk; *(int*)(list1b + 4 * s) = vo + 4 * ROWB;
        }
        *(int*)(list1b + 4 * (p1n + ln)) = 0;        // unconditional pads
        // read chunks + issue next gather (flight = tail + barrier + preamble)
        if (i < TT) {
          int4 d0a, d0b, d1a, d1b;
          asm volatile("" ::: "memory");
          READC(d0a, d0b, list1b, 0);
          READC(d1a, d1b, list1b, 1);
          ISS8Q(gA, d0a, d0b, w1zb);               // unconditional group 0
          if (p1n > 8) ISS8Q(gB, d1a, d1b, w1zb);
        }
        n1 = p1n;
      }
    }
    asm volatile("" ::: "memory");
    __builtin_amdgcn_s_barrier();
    asm volatile("" ::: "memory");
  }

  __syncthreads();
  // epilogue: exact mean (count * 2^-11) + head GEMV
  if (!isW0 && ln < 48) {
    const float r = 1.0f / 2048.0f;
    ((float4*)feat)[ln] = make_float4(cntk[0] * r, cntk[1] * r, cntk[2] * r, cntk[3] * r);
  }
  __syncthreads();
  if (tid < NCLS) {
    float a = b_head[tid];
    const float* wh = W_head + tid * HN;
    #pragma unroll 8
    for (int q = 0; q < HN; ++q) a += feat[q] * wh[q];
    out[b * NCLS + tid] = a;
  }
}

extern "C" void kernel_launch(void* const* d_in, const int* in_sizes, int n_in,
                              void* d_out, int out_size, void* d_ws, size_t ws_size,
                              hipStream_t stream) {
  const float* x       = (const float*)d_in[0];
  const float* W_in    = (const float*)d_in[1];
  const float* b_in    = (const float*)d_in[2];
  const float* W_cells = (const float*)d_in[3];
  const float* b_cells = (const float*)d_in[4];
  const float* W_head  = (const float*)d_in[5];
  const float* b_head  = (const float*)d_in[6];
  float* out = (float*)d_out;
  float* ws  = (float*)d_ws;   // 296704 bytes used

  snn_pack_k<<<(2 * HN * HN + 512 + 255) / 256, 256, 0, stream>>>(W_cells, ws);
  snn_main_k<<<128, 128, LDS_TOTAL, stream>>>(
      x, W_in, b_in, b_cells, W_head, b_head, ws, out);
}

// Round 18
// 866.510 us; speedup vs baseline: 1.1963x; 1.1963x over previous
//
#include <hip/hip_runtime.h>

#define HN 192
#define TT 2048
#define NCLS 12
#define ROWB 768
// LDS layout (bytes)
#define L0_PAD    147456           // 2048B zero region (pad reads land here)
#define LDS_LIST0 149504           // 1024B data slots + 256B junk
#define LDS_LIST1 150784           // same for layer 1
#define LDS_S0    152064           // 2 x 1024B s0 double buffer (parity)
#define LDS_FEAT  154112           // 768B
#define LDS_TOTAL 154880

// ws layout (floats): [w0 rows 0..191][zero row][w1 rows 0..191][1024B pad]
__global__ void snn_pack_k(const float* __restrict__ Wc, float* __restrict__ ws) {
  int idx = blockIdx.x * 256 + threadIdx.x;
  if (idx < HN * HN) {                       // layer 0: Wc[0][i][j] -> ws[j*192+i]
    int i = idx / HN, j = idx % HN;
    ws[j * HN + i] = Wc[idx];
  } else if (idx < 2 * HN * HN) {            // layer 1 -> rows 193..384
    int r = idx - HN * HN;
    int i = r / HN, j = r % HN;
    ws[(193 + j) * HN + i] = Wc[idx];
  } else {
    int r = idx - 2 * HN * HN;
    if (r < HN) ws[192 * HN + r] = 0.0f;     // zero row
    if (r < 256) ws[385 * HN + r] = 0.0f;    // tail pad
  }
}

__device__ __forceinline__ float4 add4(float4 a, float4 b) {
  return make_float4(a.x + b.x, a.y + b.y, a.z + b.z, a.w + b.w);
}
__device__ __forceinline__ int lanecnt_lt(unsigned long long m) {
  return __builtin_amdgcn_mbcnt_hi((unsigned)(m >> 32),
           __builtin_amdgcn_mbcnt_lo((unsigned)m, 0u));
}

#define READC(da, db, base, c) do { \
  da = *(const int4*)((base) + (c) * 32); \
  db = *(const int4*)((base) + (c) * 32 + 16); } while (0)

#define ISS8Q(p, ca, cb, basep) do { \
  p##0 = *(const float4*)((basep) + (unsigned)(ca).x + ln16); \
  p##1 = *(const float4*)((basep) + (unsigned)(ca).y + ln16); \
  p##2 = *(const float4*)((basep) + (unsigned)(ca).z + ln16); \
  p##3 = *(const float4*)((basep) + (unsigned)(ca).w + ln16); \
  p##4 = *(const float4*)((basep) + (unsigned)(cb).x + ln16); \
  p##5 = *(const float4*)((basep) + (unsigned)(cb).y + ln16); \
  p##6 = *(const float4*)((basep) + (unsigned)(cb).z + ln16); \
  p##7 = *(const float4*)((basep) + (unsigned)(cb).w + ln16); } while (0)

#define CONS8Q(acc, p) acc = add4(acc, \
  add4(add4(add4(p##0, p##1), add4(p##2, p##3)), \
       add4(add4(p##4, p##5), add4(p##6, p##7))))

// 2 waves per batch, one-step-lagged pipeline (r10 structure): wave0 layer 0
// (LDS W0 gather), wave1 layer 1 (global W1 gather, full-iteration flight).
// Branchless compaction (cndmask'd addresses into a junk region),
// unconditional pads, unconditional group-0 issue/consume, unconditional
// s0 publish (1024B slots).  One raw s_barrier per step; memory clobbers
// fence the compiler, no sched_barrier (lets the scheduler pipeline freely).
__global__ __launch_bounds__(128, 1) void snn_main_k(
    const float* __restrict__ x, const float* __restrict__ W_in,
    const float* __restrict__ b_in, const float* __restrict__ b_cells,
    const float* __restrict__ W_head, const float* __restrict__ b_head,
    const float* __restrict__ ws, float* __restrict__ out)
{
  extern __shared__ char lds[];
  const int tid = threadIdx.x;
  const int ln  = tid & 63;
  const bool isW0 = (tid < 64);
  const int b   = blockIdx.x;
  const unsigned ln16 = (unsigned)ln << 4;
  const char* ldsb = lds;
  char* list0b = lds + LDS_LIST0;
  char* list1b = lds + LDS_LIST1;
  float* feat  = (float*)(lds + LDS_FEAT);
  const char* w1zb = (const char*)ws + 192 * ROWB;   // zero row = L1 offset base

  // stage W0 (9216 float4) + 2048B zero guard (both waves)
  {
    const float4* src = (const float4*)ws;
    float4* dst = (float4*)lds;
    for (int i = tid; i < (192 * ROWB) / 16; i += 128) dst[i] = src[i];
    ((float4*)(lds + L0_PAD))[tid] = make_float4(0.f, 0.f, 0.f, 0.f);
  }
  __syncthreads();

  // opaque zero: forces x loads to VMEM so lgkm counter stays purely DS
  int vz;
  asm volatile("v_mov_b32 %0, 0" : "=v"(vz));

  // per-lane constants (4 neurons/lane in both layers; lanes 48-63 parked)
  float wi0[4], wi1[4], wi2[4], zb[4], b1z[4];
  #pragma unroll
  for (int k = 0; k < 4; ++k) {
    int i = 4 * ln + k;
    bool a = (i < HN);
    int ii = a ? i : 0;
    wi0[k] = a ? W_in[ii * 3 + 0] : 0.f;
    wi1[k] = a ? W_in[ii * 3 + 1] : 0.f;
    wi2[k] = a ? W_in[ii * 3 + 2] : 0.f;
    zb[k]  = a ? (b_in[ii] + b_cells[ii]) : -1e30f;
    b1z[k] = a ? b_cells[HN + ii] : -1e30f;
  }
  const float* __restrict__ xb = x + (size_t)b * TT * 3;
  const int vo = ln * 3072;

  // wave0 state: chunks preset to pad offsets (iter0 gathers zeros)
  float v0k[4] = {0, 0, 0, 0};
  int n0 = 0;
  int4 c0a = {L0_PAD,L0_PAD,L0_PAD,L0_PAD}, c0b = c0a, c1a = c0a, c1b = c0a;
  float x0 = xb[vz + 0], x1 = xb[vz + 1], x2 = xb[vz + 2];
  // wave1 state
  float v1k[4] = {0, 0, 0, 0}, cntk[4] = {0, 0, 0, 0};
  int n1 = 0;
  float4 gA0, gA1, gA2, gA3, gA4, gA5, gA6, gA7;
  float4 gB0, gB1, gB2, gB3, gB4, gB5, gB6, gB7;
  if (!isW0) {
    // pre-loop: issue an initial pad gather (zero row) so iter1's consume is safe
    int4 dz = {0, 0, 0, 0};
    ISS8Q(gA, dz, dz, w1zb);
    gB0=gB1=gB2=gB3=gB4=gB5=gB6=gB7=make_float4(0.f,0.f,0.f,0.f);
  }

  #pragma unroll 1
  for (int i = 0; i <= TT; ++i) {
    if (isW0) {
      if (i < TT) {
        // ======== wave 0: layer-0 step i ========
        const int wp = i & 1;
        float4 a0v = make_float4(0.f, 0.f, 0.f, 0.f);
        float4 hA0, hA1, hA2, hA3, hA4, hA5, hA6, hA7;
        float4 hB0, hB1, hB2, hB3, hB4, hB5, hB6, hB7;
        ISS8Q(hA, c0a, c0b, ldsb);             // unconditional group 0
        if (n0 > 8) ISS8Q(hB, c1a, c1b, ldsb);
        // input projection (carried x) + next-x prefetch (VMEM, in flight)
        float zarr[4];
        #pragma unroll
        for (int k = 0; k < 4; ++k)
          zarr[k] = x0 * wi0[k] + x1 * wi1[k] + x2 * wi2[k] + zb[k];
        const int tn = (i + 1 < TT) ? i + 1 : 0;
        const float nx0 = xb[tn * 3 + vz + 0];
        const float nx1 = xb[tn * 3 + vz + 1];
        const float nx2 = xb[tn * 3 + vz + 2];
        CONS8Q(a0v, hA);
        if (n0 > 8) CONS8Q(a0v, hB);
        if (n0 > 16) {                          // rare overflow: chunks 2..3 + loop
          int4 e2a, e2b;
          float4 r0, r1, r2, r3, r4, r5, r6, r7;
          READC(e2a, e2b, list0b, 2);
          ISS8Q(r, e2a, e2b, ldsb);
          CONS8Q(a0v, r);
          if (n0 > 24) {
            READC(e2a, e2b, list0b, 3);
            ISS8Q(r, e2a, e2b, ldsb);
            CONS8Q(a0v, r);
          }
          if (n0 > 32) {
            #pragma unroll 1
            for (int g = 4; g * 8 < n0; ++g) {
              READC(e2a, e2b, list0b, g);
              ISS8Q(r, e2a, e2b, ldsb);
              CONS8Q(a0v, r);
            }
          }
        }
        // LIF layer 0 (exact reference op order), flattened
        const float a0arr[4] = {a0v.x, a0v.y, a0v.z, a0v.w};
        float s0f[4];
        bool sp[4];
        unsigned long long mm0, mm1, mm2, mm3;
        {
          float u, v;
          u = zarr[0] + a0arr[0]; v = v0k[0] + (u - v0k[0]) * 0.5f;
          sp[0] = (v >= 1.0f); mm0 = __ballot(sp[0] ? 1 : 0);
          s0f[0] = sp[0] ? 1.0f : 0.0f; v0k[0] = sp[0] ? 0.0f : v;
          u = zarr[1] + a0arr[1]; v = v0k[1] + (u - v0k[1]) * 0.5f;
          sp[1] = (v >= 1.0f); mm1 = __ballot(sp[1] ? 1 : 0);
          s0f[1] = sp[1] ? 1.0f : 0.0f; v0k[1] = sp[1] ? 0.0f : v;
          u = zarr[2] + a0arr[2]; v = v0k[2] + (u - v0k[2]) * 0.5f;
          sp[2] = (v >= 1.0f); mm2 = __ballot(sp[2] ? 1 : 0);
          s0f[2] = sp[2] ? 1.0f : 0.0f; v0k[2] = sp[2] ? 0.0f : v;
          u = zarr[3] + a0arr[3]; v = v0k[3] + (u - v0k[3]) * 0.5f;
          sp[3] = (v >= 1.0f); mm3 = __ballot(sp[3] ? 1 : 0);
          s0f[3] = sp[3] ? 1.0f : 0.0f; v0k[3] = sp[3] ? 0.0f : v;
        }
        // publish s0(i) — unconditional (1024B slot; parked lanes write 0)
        *(float4*)(lds + LDS_S0 + (wp << 10) + ln16) =
            make_float4(s0f[0], s0f[1], s0f[2], s0f[3]);
        // branchless compaction: cndmask'd slot (junk slots at 256+ln)
        const int q0   = (int)__popcll(mm0);
        const int q01  = q0  + (int)__popcll(mm1);
        const int q012 = q01 + (int)__popcll(mm2);
        const int p0n  = q012 + (int)__popcll(mm3);
        const int jk = 256 + ln;
        {
          int s;
          s = sp[0] ? lanecnt_lt(mm0)          : jk; *(int*)(list0b + 4 * s) = vo;
          s = sp[1] ? (q0   + lanecnt_lt(mm1)) : jk; *(int*)(list0b + 4 * s) = vo + ROWB;
          s = sp[2] ? (q01  + lanecnt_lt(mm2)) : jk; *(int*)(list0b + 4 * s) = vo + 2 * ROWB;
          s = sp[3] ? (q012 + lanecnt_lt(mm3)) : jk; *(int*)(list0b + 4 * s) = vo + 3 * ROWB;
        }
        *(int*)(list0b + 4 * (p0n + ln)) = L0_PAD;   // unconditional pads
        n0 = p0n;
        asm volatile("" ::: "memory");
        READC(c0a, c0b, list0b, 0);
        READC(c1a, c1b, list0b, 1);
        // oldest DS ops (s0 publish, compaction) retired; chunk reads stay out
        asm volatile("s_waitcnt lgkmcnt(8)" ::: "memory");
        x0 = nx0; x1 = nx1; x2 = nx2;
      }
    } else {
      if (i > 0) {
        // ======== wave 1: layer-1 step i-1 ========
        const int rp = (i - 1) & 1;
        const float4 s0v = *(const float4*)(lds + LDS_S0 + (rp << 10) + ln16);
        // consume W1 gather (issued at end of previous block -> real flight)
        float4 a1v = make_float4(0.f, 0.f, 0.f, 0.f);
        CONS8Q(a1v, gA);                        // unconditional group 0
        if (n1 > 8) CONS8Q(a1v, gB);
        if (n1 > 16) {                          // rare overflow
          int4 e2a, e2b;
          float4 r0, r1, r2, r3, r4, r5, r6, r7;
          READC(e2a, e2b, list1b, 2);
          ISS8Q(r, e2a, e2b, w1zb);
          CONS8Q(a1v, r);
          if (n1 > 24) {
            READC(e2a, e2b, list1b, 3);
            ISS8Q(r, e2a, e2b, w1zb);
            CONS8Q(a1v, r);
          }
          if (n1 > 32) {
            #pragma unroll 1
            for (int g = 4; g * 8 < n1; ++g) {
              READC(e2a, e2b, list1b, g);
              ISS8Q(r, e2a, e2b, w1zb);
              CONS8Q(a1v, r);
            }
          }
        }
        // LIF layer 1, flattened
        const float a1arr[4] = {a1v.x + s0v.x, a1v.y + s0v.y,
                                a1v.z + s0v.z, a1v.w + s0v.w};
        float s1w[4];
        bool sq[4];
        unsigned long long nn0, nn1, nn2, nn3;
        {
          float u, v;
          u = b1z[0] + a1arr[0]; v = v1k[0] + (u - v1k[0]) * 0.5f;
          sq[0] = (v >= 1.0f); nn0 = __ballot(sq[0] ? 1 : 0);
          s1w[0] = sq[0] ? 1.0f : 0.0f; v1k[0] = sq[0] ? 0.0f : v;
          u = b1z[1] + a1arr[1]; v = v1k[1] + (u - v1k[1]) * 0.5f;
          sq[1] = (v >= 1.0f); nn1 = __ballot(sq[1] ? 1 : 0);
          s1w[1] = sq[1] ? 1.0f : 0.0f; v1k[1] = sq[1] ? 0.0f : v;
          u = b1z[2] + a1arr[2]; v = v1k[2] + (u - v1k[2]) * 0.5f;
          sq[2] = (v >= 1.0f); nn2 = __ballot(sq[2] ? 1 : 0);
          s1w[2] = sq[2] ? 1.0f : 0.0f; v1k[2] = sq[2] ? 0.0f : v;
          u = b1z[3] + a1arr[3]; v = v1k[3] + (u - v1k[3]) * 0.5f;
          sq[3] = (v >= 1.0f); nn3 = __ballot(sq[3] ? 1 : 0);
          s1w[3] = sq[3] ? 1.0f : 0.0f; v1k[3] = sq[3] ? 0.0f : v;
        }
        cntk[0] += s1w[0]; cntk[1] += s1w[1]; cntk[2] += s1w[2]; cntk[3] += s1w[3];
        // branchless compaction (junk slots at 256+ln; pad value 0 -> zero row)
        const int r0c  = (int)__popcll(nn0);
        const int r01  = r0c + (int)__popcll(nn1);
        const int r012 = r01 + (int)__popcll(nn2);
        const int p1n  = r012 + (int)__popcll(nn3);
        const int jk = 256 + ln;
        {
          int s;
          s = sq[0] ? lanecnt_lt(nn0)          : jk; *(int*)(list1b + 4 * s) = vo + ROWB;
          s = sq[1] ? (r0c  + lanecnt_lt(nn1)) : jk; *(int*)(list1b + 4 * s) = vo + 2 * ROWB;
          s = sq[2] ? (r01  + lanecnt_lt(nn2)) : jk; *(int*)(list1b + 4 * s) = vo + 3 * ROWB;
          s = sq[3] ? (r012 + lanecnt_lt(nn3)) : jk; *(int*)(list1b + 4 * s) = vo + 4 * ROWB;
        }
        *(int*)(list1b + 4 * (p1n + ln)) = 0;        // unconditional pads
        // read chunks + issue next gather (flight = tail + barrier + preamble)
        if (i < TT) {
          int4 d0a, d0b, d1a, d1b;
          asm volatile("" ::: "memory");
          READC(d0a, d0b, list1b, 0);
          READC(d1a, d1b, list1b, 1);
          ISS8Q(gA, d0a, d0b, w1zb);               // unconditional group 0
          if (p1n > 8) ISS8Q(gB, d1a, d1b, w1zb);
        }
        n1 = p1n;
      }
    }
    asm volatile("" ::: "memory");
    __builtin_amdgcn_s_barrier();
    asm volatile("" ::: "memory");
  }

  __syncthreads();
  // epilogue: exact mean (count * 2^-11) + head GEMV
  if (!isW0 && ln < 48) {
    const float r = 1.0f / 2048.0f;
    ((float4*)feat)[ln] = make_float4(cntk[0] * r, cntk[1] * r, cntk[2] * r, cntk[3] * r);
  }
  __syncthreads();
  if (tid < NCLS) {
    float a = b_head[tid];
    const float* wh = W_head + tid * HN;
    #pragma unroll 8
    for (int q = 0; q < HN; ++q) a += feat[q] * wh[q];
    out[b * NCLS + tid] = a;
  }
}

extern "C" void kernel_launch(void* const* d_in, const int* in_sizes, int n_in,
                              void* d_out, int out_size, void* d_ws, size_t ws_size,
                              hipStream_t stream) {
  const float* x       = (const float*)d_in[0];
  const float* W_in    = (const float*)d_in[1];
  const float* b_in    = (const float*)d_in[2];
  const float* W_cells = (const float*)d_in[3];
  const float* b_cells = (const float*)d_in[4];
  const float* W_head  = (const float*)d_in[5];
  const float* b_head  = (const float*)d_in[6];
  float* out = (float*)d_out;
  float* ws  = (float*)d_ws;   // 296704 bytes used

  snn_pack_k<<<(2 * HN * HN + 512 + 255) / 256, 256, 0, stream>>>(W_cells, ws);
  snn_main_k<<<128, 128, LDS_TOTAL, stream>>>(
      x, W_in, b_in, b_cells, W_head, b_head, ws, out);
}